// Round 1
// baseline (891.869 us; speedup 1.0000x reference)
//
#include <hip/hip_runtime.h>

// Sizes (fixed by the reference problem)
#define BB 2048   // batch
#define TT 512    // time steps
#define II 64     // input features
#define GG 9      // 3*H gates
#define XWS 12    // padded floats per (t,b) in workspace (16B-aligned float4 x3)

// ---------------------------------------------------------------------------
// Kernel 1: xw[t][b][g] = b_ih0[g] + sum_i x[b][t][i] * W_ih0[g][i]
// Memory-bound: reads 256 MB of x. Thread mapping b-fast for coalesced writes.
// ---------------------------------------------------------------------------
__global__ __launch_bounds__(256) void xw_kernel(
    const float* __restrict__ x, const float* __restrict__ W_ih0,
    const float* __restrict__ b_ih0, float* __restrict__ xw)
{
    __shared__ float wt[II * XWS];   // W transposed: wt[i][g], padded stride 12
    __shared__ float bias[XWS];
    const int tid = threadIdx.x;

    for (int idx = tid; idx < GG * II; idx += 256) {
        int g = idx >> 6;         // W_ih0 is [9][64]
        int i = idx & 63;
        wt[i * XWS + g] = W_ih0[idx];
    }
    if (tid < GG) bias[tid] = b_ih0[tid];
    __syncthreads();

    const int b = blockIdx.x * 256 + tid;
    const int t = blockIdx.y;
    const float* xrow = x + ((size_t)b * TT + t) * II;

    float acc[GG];
#pragma unroll
    for (int g = 0; g < GG; ++g) acc[g] = bias[g];

#pragma unroll
    for (int i0 = 0; i0 < II; i0 += 4) {
        float4 xv = *(const float4*)(xrow + i0);
        float xs[4] = {xv.x, xv.y, xv.z, xv.w};
#pragma unroll
        for (int di = 0; di < 4; ++di) {
            const float* wrow = &wt[(i0 + di) * XWS];
            const float v = xs[di];
#pragma unroll
            for (int g = 0; g < GG; ++g) acc[g] = fmaf(v, wrow[g], acc[g]);
        }
    }

    float* o = xw + ((size_t)t * BB + b) * XWS;
    *(float4*)(o)     = make_float4(acc[0], acc[1], acc[2], acc[3]);
    *(float4*)(o + 4) = make_float4(acc[4], acc[5], acc[6], acc[7]);
    *(float4*)(o + 8) = make_float4(acc[8], 0.f, 0.f, 0.f);
}

// ---------------------------------------------------------------------------
// Kernel 2: fused 2-layer GRU recurrence, one thread per sequence.
// 32 blocks x 64 threads. Software-pipelined xw prefetch (4+4 steps).
// ---------------------------------------------------------------------------
__device__ __forceinline__ float sigf(float v) {
    return __fdividef(1.f, 1.f + __expf(-v));
}
__device__ __forceinline__ float tanhff(float v) {
    // tanh(v) = 1 - 2/(exp(2v)+1); saturates correctly at +/-inf
    return 1.f - __fdividef(2.f, __expf(2.f * v) + 1.f);
}

__global__ __launch_bounds__(64, 1) void gru_rec(
    const float* __restrict__ xw,
    const float* __restrict__ W_hh0, const float* __restrict__ b_hh0,
    const float* __restrict__ W_ih1, const float* __restrict__ b_ih1,
    const float* __restrict__ W_hh1, const float* __restrict__ b_hh1,
    float* __restrict__ out)
{
    const int b = blockIdx.x * 64 + threadIdx.x;

    // Weights into registers (uniform -> mostly scalar regs)
    float wh0[GG][3], wi1[GG][3], wh1[GG][3], bh0[GG], bi1[GG], bh1[GG];
#pragma unroll
    for (int g = 0; g < GG; ++g) {
#pragma unroll
        for (int j = 0; j < 3; ++j) {
            wh0[g][j] = W_hh0[g * 3 + j];
            wi1[g][j] = W_ih1[g * 3 + j];
            wh1[g][j] = W_hh1[g * 3 + j];
        }
        bh0[g] = b_hh0[g];
        bi1[g] = b_ih1[g];
        bh1[g] = b_hh1[g];
    }

    float h0[3] = {0.f, 0.f, 0.f};
    float h1[3] = {0.f, 0.f, 0.f};

    float4 A[4][3], Bf[4][3];

    auto ld = [&](float4 (&dst)[4][3], int t0) {
#pragma unroll
        for (int k = 0; k < 4; ++k) {
            int t = t0 + k;
            t = (t < TT) ? t : (TT - 1);   // clamp tail (values unused)
            const float4* p = (const float4*)(xw + ((size_t)t * BB + b) * XWS);
            dst[k][0] = p[0];
            dst[k][1] = p[1];
            dst[k][2] = p[2];
        }
    };

    auto step = [&](const float4 (&bu)[4][3], int k) {
        float w[GG] = {bu[k][0].x, bu[k][0].y, bu[k][0].z, bu[k][0].w,
                       bu[k][1].x, bu[k][1].y, bu[k][1].z, bu[k][1].w,
                       bu[k][2].x};
        // ----- layer 0 -----
        float g0[GG];
#pragma unroll
        for (int g = 0; g < GG; ++g)
            g0[g] = fmaf(wh0[g][2], h0[2],
                    fmaf(wh0[g][1], h0[1],
                    fmaf(wh0[g][0], h0[0], bh0[g])));
        float r0 = sigf(w[0] + g0[0]), r1 = sigf(w[1] + g0[1]), r2 = sigf(w[2] + g0[2]);
        float z0 = sigf(w[3] + g0[3]), z1 = sigf(w[4] + g0[4]), z2 = sigf(w[5] + g0[5]);
        float n0 = tanhff(fmaf(r0, g0[6], w[6]));
        float n1 = tanhff(fmaf(r1, g0[7], w[7]));
        float n2 = tanhff(fmaf(r2, g0[8], w[8]));
        h0[0] = fmaf(z0, h0[0] - n0, n0);
        h0[1] = fmaf(z1, h0[1] - n1, n1);
        h0[2] = fmaf(z2, h0[2] - n2, n2);
        // ----- layer 1 -----
        float a[GG], g1[GG];
#pragma unroll
        for (int g = 0; g < GG; ++g) {
            a[g]  = fmaf(wi1[g][2], h0[2],
                    fmaf(wi1[g][1], h0[1],
                    fmaf(wi1[g][0], h0[0], bi1[g])));
            g1[g] = fmaf(wh1[g][2], h1[2],
                    fmaf(wh1[g][1], h1[1],
                    fmaf(wh1[g][0], h1[0], bh1[g])));
        }
        float s0 = sigf(a[0] + g1[0]), s1 = sigf(a[1] + g1[1]), s2 = sigf(a[2] + g1[2]);
        float u0 = sigf(a[3] + g1[3]), u1 = sigf(a[4] + g1[4]), u2 = sigf(a[5] + g1[5]);
        float m0 = tanhff(fmaf(s0, g1[6], a[6]));
        float m1 = tanhff(fmaf(s1, g1[7], a[7]));
        float m2 = tanhff(fmaf(s2, g1[8], a[8]));
        h1[0] = fmaf(u0, h1[0] - m0, m0);
        h1[1] = fmaf(u1, h1[1] - m1, m1);
        h1[2] = fmaf(u2, h1[2] - m2, m2);
    };

    ld(A, 0);
    for (int t0 = 0; t0 < TT; t0 += 8) {
        ld(Bf, t0 + 4);            // prefetch steps t0+4..t0+7
#pragma unroll
        for (int k = 0; k < 4; ++k) step(A, k);
        ld(A, t0 + 8);             // prefetch steps t0+8..t0+11 (clamped at end)
#pragma unroll
        for (int k = 0; k < 4; ++k) step(Bf, k);
    }

    out[b * 3 + 0] = h1[0];
    out[b * 3 + 1] = h1[1];
    out[b * 3 + 2] = h1[2];
}

// ---------------------------------------------------------------------------
extern "C" void kernel_launch(void* const* d_in, const int* in_sizes, int n_in,
                              void* d_out, int out_size, void* d_ws, size_t ws_size,
                              hipStream_t stream) {
    const float* x     = (const float*)d_in[0];
    const float* W_ih0 = (const float*)d_in[1];
    const float* W_hh0 = (const float*)d_in[2];
    const float* b_ih0 = (const float*)d_in[3];
    const float* b_hh0 = (const float*)d_in[4];
    const float* W_ih1 = (const float*)d_in[5];
    const float* W_hh1 = (const float*)d_in[6];
    const float* b_ih1 = (const float*)d_in[7];
    const float* b_hh1 = (const float*)d_in[8];
    float* out = (float*)d_out;
    float* xw  = (float*)d_ws;   // needs 512*2048*12*4 = 48 MiB

    hipLaunchKernelGGL(xw_kernel, dim3(BB / 256, TT), dim3(256), 0, stream,
                       x, W_ih0, b_ih0, xw);
    hipLaunchKernelGGL(gru_rec, dim3(BB / 64), dim3(64), 0, stream,
                       xw, W_hh0, b_hh0, W_ih1, b_ih1, W_hh1, b_hh1, out);
}

// Round 2
// 649.879 us; speedup vs baseline: 1.3724x; 1.3724x over previous
//
#include <hip/hip_runtime.h>

#define BB 2048   // batch
#define TT 512    // time steps
#define II 64     // input features
#define XWS 12    // floats per (b,t): 3 x (r,z,n,pad), pre-scaled for exp2

#define LOG2E 1.44269504088896340736f

__device__ __forceinline__ float fexp2(float x) {
#if __has_builtin(__builtin_amdgcn_exp2f)
    return __builtin_amdgcn_exp2f(x);
#else
    return __expf(x * 0.69314718055994531f);
#endif
}
__device__ __forceinline__ float frcp(float x) {
#if __has_builtin(__builtin_amdgcn_rcpf)
    return __builtin_amdgcn_rcpf(x);
#else
    return __fdividef(1.f, x);
#endif
}

// quad broadcasts: every lane gets lane {0,1,2} of its 4-lane quad
#define QB0(v) __int_as_float(__builtin_amdgcn_mov_dpp(__float_as_int(v), 0x00, 0xF, 0xF, 1))
#define QB1(v) __int_as_float(__builtin_amdgcn_mov_dpp(__float_as_int(v), 0x55, 0xF, 0xF, 1))
#define QB2(v) __int_as_float(__builtin_amdgcn_mov_dpp(__float_as_int(v), 0xAA, 0xF, 0xF, 1))

// ---------------------------------------------------------------------------
// K1: xw[b][t][4j+c] = scale_c * (b_ih0[c*3+j] + sum_i x[b,t,i] W_ih0[c*3+j, i])
//     scale = -log2e for r,z rows; +2*log2e for n rows.
// Lane -> row (b*512+t): consecutive lanes = consecutive t -> wave reads a
// contiguous 16KB window of x and writes a contiguous 3KB chunk of xw.
// ---------------------------------------------------------------------------
__global__ __launch_bounds__(256) void xw_kernel(
    const float* __restrict__ x, const float* __restrict__ W_ih0,
    const float* __restrict__ b_ih0, float* __restrict__ xw)
{
    __shared__ float wt[II * XWS];   // [i][4j+c], pre-scaled
    __shared__ float bias[XWS];
    const int tid = threadIdx.x;

    for (int idx = tid; idx < 9 * II; idx += 256) {
        int i = idx & 63, g = idx >> 6;     // W_ih0 row g = c*3 + j
        int c = g / 3, j = g - c * 3;
        float sc = (c == 2) ? (2.0f * LOG2E) : (-LOG2E);
        wt[i * XWS + j * 4 + c] = W_ih0[idx] * sc;
    }
    if (tid < XWS) {
        int j = tid >> 2, c = tid & 3;
        float v = 0.f;
        if (c < 3) {
            float sc = (c == 2) ? (2.0f * LOG2E) : (-LOG2E);
            v = b_ih0[c * 3 + j] * sc;
        }
        bias[tid] = v;
    }
    __syncthreads();

    const int R = blockIdx.x * 256 + tid;        // row = b*512 + t
    const float* xr = x + (size_t)R * II;

    float a[XWS];
#pragma unroll
    for (int u = 0; u < XWS; ++u) a[u] = bias[u];

#pragma unroll
    for (int i0 = 0; i0 < II; i0 += 4) {
        float4 xv = *(const float4*)(xr + i0);
        float xs[4] = {xv.x, xv.y, xv.z, xv.w};
#pragma unroll
        for (int d = 0; d < 4; ++d) {
            const float4* w4 = (const float4*)&wt[(i0 + d) * XWS];
            float4 w0 = w4[0], w1 = w4[1], w2 = w4[2];
            float v = xs[d];
            a[0] = fmaf(v, w0.x, a[0]);
            a[1] = fmaf(v, w0.y, a[1]);
            a[2] = fmaf(v, w0.z, a[2]);
            a[4] = fmaf(v, w1.x, a[4]);
            a[5] = fmaf(v, w1.y, a[5]);
            a[6] = fmaf(v, w1.z, a[6]);
            a[8] = fmaf(v, w2.x, a[8]);
            a[9] = fmaf(v, w2.y, a[9]);
            a[10] = fmaf(v, w2.z, a[10]);
        }
    }

    float* o = xw + (size_t)R * XWS;
    *(float4*)(o + 0) = make_float4(a[0], a[1], a[2], 0.f);
    *(float4*)(o + 4) = make_float4(a[4], a[5], a[6], 0.f);
    *(float4*)(o + 8) = make_float4(a[8], a[9], a[10], 0.f);
}

// ---------------------------------------------------------------------------
// K2: fused 2-layer GRU recurrence. 4 lanes per sequence (lane j owns h[j],
// lane 3 spare). h rebroadcast within the quad via DPP quad_perm. 4-deep
// static-index register prefetch of the per-step float4.
// ---------------------------------------------------------------------------
__global__ __launch_bounds__(512) void gru_rec(
    const float* __restrict__ xw,
    const float* __restrict__ W_hh0, const float* __restrict__ b_hh0,
    const float* __restrict__ W_ih1, const float* __restrict__ b_ih1,
    const float* __restrict__ W_hh1, const float* __restrict__ b_hh1,
    float* __restrict__ out)
{
    const int tid = threadIdx.x;
    const int j   = tid & 3;
    const int jj  = (j < 3) ? j : 2;                    // lane 3 mirrors lane 2
    const int s   = (blockIdx.x * 512 + tid) >> 2;      // sequence index

    // per-lane pre-scaled weights (rows c*3+jj), c in {r,z,n}
    float wh0[3][3], wi1[3][3], wh1[3][3], bh0[3], bi1[3], bh1[3];
#pragma unroll
    for (int c = 0; c < 3; ++c) {
        float sc = (c == 2) ? (2.0f * LOG2E) : (-LOG2E);
        int row = c * 3 + jj;
#pragma unroll
        for (int k = 0; k < 3; ++k) {
            wh0[c][k] = W_hh0[row * 3 + k] * sc;
            wi1[c][k] = W_ih1[row * 3 + k] * sc;
            wh1[c][k] = W_hh1[row * 3 + k] * sc;
        }
        bh0[c] = b_hh0[row] * sc;
        bi1[c] = b_ih1[row] * sc;
        bh1[c] = b_hh1[row] * sc;
    }

    float h00 = 0.f, h01 = 0.f, h02 = 0.f;   // broadcast copies of h0
    float h10 = 0.f, h11 = 0.f, h12 = 0.f;   // broadcast copies of h1
    float h0j = 0.f, h1j = 0.f;              // this lane's own element

    const float* base = xw + ((size_t)s * TT) * XWS + jj * 4;

    auto LD = [&](int t) -> float4 {
        t = (t < TT) ? t : (TT - 1);
        return *(const float4*)(base + (size_t)t * XWS);
    };

    auto STEP = [&](float4 xq) {
        // ----- layer 0 -----
        float hr = fmaf(wh0[0][2], h02, fmaf(wh0[0][1], h01, fmaf(wh0[0][0], h00, bh0[0])));
        float hz = fmaf(wh0[1][2], h02, fmaf(wh0[1][1], h01, fmaf(wh0[1][0], h00, bh0[1])));
        float hn = fmaf(wh0[2][2], h02, fmaf(wh0[2][1], h01, fmaf(wh0[2][0], h00, bh0[2])));
        float r = frcp(1.f + fexp2(xq.x + hr));                   // sigmoid
        float z = frcp(1.f + fexp2(xq.y + hz));                   // sigmoid
        float q = fmaf(r, hn, xq.z);
        float n = fmaf(-2.f, frcp(1.f + fexp2(q)), 1.f);          // tanh
        h0j = fmaf(z, h0j - n, n);
        h00 = QB0(h0j); h01 = QB1(h0j); h02 = QB2(h0j);
        // ----- layer 1 -----
        float a0 = fmaf(wi1[0][2], h02, fmaf(wi1[0][1], h01, fmaf(wi1[0][0], h00, bi1[0])));
        float a1 = fmaf(wi1[1][2], h02, fmaf(wi1[1][1], h01, fmaf(wi1[1][0], h00, bi1[1])));
        float a2 = fmaf(wi1[2][2], h02, fmaf(wi1[2][1], h01, fmaf(wi1[2][0], h00, bi1[2])));
        float g0 = fmaf(wh1[0][2], h12, fmaf(wh1[0][1], h11, fmaf(wh1[0][0], h10, bh1[0])));
        float g1 = fmaf(wh1[1][2], h12, fmaf(wh1[1][1], h11, fmaf(wh1[1][0], h10, bh1[1])));
        float g2 = fmaf(wh1[2][2], h12, fmaf(wh1[2][1], h11, fmaf(wh1[2][0], h10, bh1[2])));
        float r1 = frcp(1.f + fexp2(a0 + g0));
        float z1 = frcp(1.f + fexp2(a1 + g1));
        float q1 = fmaf(r1, g2, a2);
        float n1 = fmaf(-2.f, frcp(1.f + fexp2(q1)), 1.f);
        h1j = fmaf(z1, h1j - n1, n1);
        h10 = QB0(h1j); h11 = QB1(h1j); h12 = QB2(h1j);
    };

    float4 P0 = LD(0), P1 = LD(1), P2 = LD(2), P3 = LD(3);
    for (int t = 0; t < TT; t += 4) {
        float4 N0 = LD(t + 4), N1 = LD(t + 5), N2 = LD(t + 6), N3 = LD(t + 7);
        STEP(P0); STEP(P1); STEP(P2); STEP(P3);
        P0 = N0; P1 = N1; P2 = N2; P3 = N3;
    }

    if (j < 3) out[s * 3 + j] = h1j;
}

// ---------------------------------------------------------------------------
extern "C" void kernel_launch(void* const* d_in, const int* in_sizes, int n_in,
                              void* d_out, int out_size, void* d_ws, size_t ws_size,
                              hipStream_t stream) {
    const float* x     = (const float*)d_in[0];
    const float* W_ih0 = (const float*)d_in[1];
    const float* W_hh0 = (const float*)d_in[2];
    const float* b_ih0 = (const float*)d_in[3];
    const float* b_hh0 = (const float*)d_in[4];
    const float* W_ih1 = (const float*)d_in[5];
    const float* W_hh1 = (const float*)d_in[6];
    const float* b_ih1 = (const float*)d_in[7];
    const float* b_hh1 = (const float*)d_in[8];
    float* out = (float*)d_out;
    float* xw  = (float*)d_ws;   // 2048*512*12*4 = 48 MiB

    hipLaunchKernelGGL(xw_kernel, dim3((BB * TT) / 256), dim3(256), 0, stream,
                       x, W_ih0, b_ih0, xw);
    hipLaunchKernelGGL(gru_rec, dim3((BB * 4) / 512), dim3(512), 0, stream,
                       xw, W_hh0, b_hh0, W_ih1, b_ih1, W_hh1, b_hh1, out);
}